// Round 6
// baseline (1144.776 us; speedup 1.0000x reference)
//
#include <hip/hip_runtime.h>
#include <hip/hip_bf16.h>
#include <cmath>

#define NA 20000
#define NS 4
#define NE 8
#define DD 1008    // aev dim (126*8)
#define D0 256
#define D1 192
#define D2 160
#define RP 20096   // padded H0 rows per ensemble member

typedef unsigned short u16;
typedef unsigned int u32;
typedef unsigned long long u64;
typedef u16 u16x8 __attribute__((ext_vector_type(8)));
typedef u16 u16x4 __attribute__((ext_vector_type(4)));
typedef float f32x4 __attribute__((ext_vector_type(4)));
typedef short s16x8 __attribute__((ext_vector_type(8)));

__device__ __forceinline__ float bf2f(u16 h) {
  u32 u = ((u32)h) << 16;
  return __builtin_bit_cast(float, u);
}
__device__ __forceinline__ u16 f2bf(float f) {  // RNE
  u32 b = __builtin_bit_cast(u32, f);
  u32 lsb = (b >> 16) & 1;
  return (u16)((b + 0x7fffu + lsb) >> 16);
}
__device__ __forceinline__ float celu_f(float x) {
  return x > 0.f ? x : 0.1f * expm1f(10.f * x);
}
__device__ __forceinline__ float gf(const void* g, size_t i, bool isF32) {
  return isF32 ? ((const float*)g)[i] : bf2f(((const u16*)g)[i]);
}
__device__ __forceinline__ int get_species(const void* sp, int i, bool i64) {
  int s = i64 ? ((const int*)sp)[2 * i] : ((const int*)sp)[i];
  return s < 0 ? 0 : (s > 3 ? 3 : s);
}
// dtype-adaptive 8-elem bf16 granule from aev (granule-aligned; DD%8==0)
__device__ __forceinline__ u16x8 loadA8(const void* aev, int atom, int kg, bool isF32) {
  u16x8 v = {0, 0, 0, 0, 0, 0, 0, 0};
  if (atom >= 0 && kg < DD) {
    if (isF32) {
      const float* p = (const float*)aev + (size_t)atom * DD + kg;
      f32x4 f0 = *(const f32x4*)p;
      f32x4 f1 = *(const f32x4*)(p + 4);
      v[0] = f2bf(f0[0]); v[1] = f2bf(f0[1]); v[2] = f2bf(f0[2]); v[3] = f2bf(f0[3]);
      v[4] = f2bf(f1[0]); v[5] = f2bf(f1[1]); v[6] = f2bf(f1[2]); v[7] = f2bf(f1[3]);
    } else {
      v = *(const u16x8*)((const u16*)aev + (size_t)atom * DD + kg);
    }
  }
  return v;
}

// ws ints: [0..3] species counts, [4..7] cursors, [13..16] atom-base prefix,
// [17] f32 accum, [18] fp32-flag, [19] i64-flag. order at int offset 1024.
// ---- k_sort: probe dtypes + count + scan + scatter, one block ----
__global__ __launch_bounds__(1024) void k_sort(const void* __restrict__ aev,
                                               const void* __restrict__ species,
                                               int* __restrict__ w, int* __restrict__ order) {
  __shared__ int cnt[4], cur[4], sh[2];
  const int tid = threadIdx.x;
  const int lane = tid & 63;
  if (tid < 4) { cnt[tid] = 0; cur[tid] = 0; }
  if (tid < 2) sh[tid] = 0;
  if (tid == 0) w[17] = 0;  // zero energy accumulator
  __syncthreads();
  if (tid < 256) {
    const u16* a = (const u16*)aev;
    int bad = 0;
    for (int i = 0; i < 16; ++i) {
      u16 h = a[tid * 16 + i];
      int ex = (h >> 7) & 0xFF;
      if (ex < 107 || ex > 147) ++bad;
    }
    atomicAdd(&sh[0], bad);
    const int* sp = (const int*)species;
    int odd = 0;
    for (int i = 0; i < 4; ++i)
      if (sp[(tid * 4 + i) * 2 + 1] != 0) ++odd;
    atomicAdd(&sh[1], odd);
  }
  __syncthreads();
  const bool isF32 = sh[0] > 400;
  const bool i64 = sh[1] == 0;
  if (tid == 0) { w[18] = isF32 ? 1 : 0; w[19] = i64 ? 1 : 0; }
  // count (wave-aggregated LDS atomics)
  for (int i = tid; i < ((NA + 1023) & ~1023); i += 1024) {
    int s = (i < NA) ? get_species(species, i, i64) : -1;
    for (int sp = 0; sp < 4; ++sp) {
      u64 m = __ballot(s == sp);
      if (m != 0 && lane == (__ffsll((long long)m) - 1))
        atomicAdd(&cnt[sp], __popcll(m));
    }
  }
  __syncthreads();
  if (tid == 0) {
    int b = 0;
    for (int s = 0; s < 4; ++s) { w[13 + s] = b; w[s] = cnt[s]; b += cnt[s]; }
  }
  __syncthreads();
  // scatter
  for (int i = tid; i < ((NA + 1023) & ~1023); i += 1024) {
    int s = (i < NA) ? get_species(species, i, i64) : -1;
    for (int sp = 0; sp < 4; ++sp) {
      u64 m = __ballot(s == sp);
      if (m == 0) continue;
      int leader = __ffsll((long long)m) - 1;
      int base = 0;
      if (lane == leader) base = atomicAdd(&cur[sp], __popcll(m));
      base = __shfl(base, leader);
      if (s == sp) {
        int rank = __popcll(m & ((lane == 63) ? 0x7fffffffffffffffULL : ((1ULL << lane) - 1)));
        order[w[13 + sp] + base + rank] = i;
      }
    }
  }
}

// ---- k_prep: all weight transposes ([se][K][N] -> bf16 [se][N][Kpad]) + smalls ----
__global__ void k_prep(const void* __restrict__ W0, const void* __restrict__ W1,
                       const void* __restrict__ W2, const void* __restrict__ b0,
                       const void* __restrict__ b1, const void* __restrict__ b2,
                       const void* __restrict__ b3, const void* __restrict__ W3,
                       u16* __restrict__ wt0, u16* __restrict__ wt1, u16* __restrict__ wt2,
                       u16* __restrict__ b0b, u16* __restrict__ b1b, u16* __restrict__ b2b,
                       u16* __restrict__ b3b, u16* __restrict__ w3b,
                       const int* __restrict__ w) {
  __shared__ u16 tile[64][68];
  const bool isF32 = (w[18] != 0);
  const int t = threadIdx.x;
  int b = blockIdx.x;
  const void* src;
  u16* dst;
  int se, kb, nb, K, N, KP;
  if (b < 2048) {
    se = b >> 6; kb = (b >> 2) & 15; nb = b & 3;
    src = W0; dst = wt0; K = 1008; N = 256; KP = 1024;
  } else if (b < 2432) {
    int i = b - 2048; se = i / 12; int r = i % 12; kb = r / 3; nb = r % 3;
    src = W1; dst = wt1; K = 256; N = 192; KP = 256;
  } else if (b < 2720) {
    int i = b - 2432; se = i / 9; int r = i % 9; kb = r / 3; nb = r % 3;
    src = W2; dst = wt2; K = 192; N = 160; KP = 192;
  } else {
    for (int i = t; i < 32 * 256; i += 256) b0b[i] = f2bf(gf(b0, i, isF32));
    for (int i = t; i < 32 * 192; i += 256) b1b[i] = f2bf(gf(b1, i, isF32));
    for (int i = t; i < 32 * 160; i += 256) b2b[i] = f2bf(gf(b2, i, isF32));
    for (int i = t; i < 32 * 160; i += 256) w3b[i] = f2bf(gf(W3, i, isF32));
    if (t < 32) b3b[t] = f2bf(gf(b3, t, isF32));
    return;
  }
  const int k0 = kb * 64, n0 = nb * 64;
  const size_t inBase = (size_t)se * K * N;
#pragma unroll
  for (int c = 0; c < 4; ++c) {
    int kk = (t >> 4) + c * 16, nn = (t & 15) * 4;
    int k = k0 + kk, n = n0 + nn;
    u16x4 v = {0, 0, 0, 0};
    if (k < K && n < N) {
      if (isF32) {
        f32x4 f = *(const f32x4*)((const float*)src + inBase + (size_t)k * N + n);
        v[0] = f2bf(f[0]); v[1] = f2bf(f[1]); v[2] = f2bf(f[2]); v[3] = f2bf(f[3]);
      } else {
        v = *(const u16x4*)((const u16*)src + inBase + (size_t)k * N + n);
      }
    }
    *(u16x4*)(&tile[kk][nn]) = v;
  }
  __syncthreads();
  int nloc = t >> 2, ks = (t & 3) * 16;
  if (n0 + nloc < N) {
    u16x8 o0, o1;
#pragma unroll
    for (int i = 0; i < 8; ++i) { o0[i] = tile[ks + i][nloc]; o1[i] = tile[ks + 8 + i][nloc]; }
    size_t ob = (size_t)se * N * KP + (size_t)(n0 + nloc) * KP + k0 + ks;
    *(u16x8*)(dst + ob) = o0;
    *(u16x8*)(dst + ob + 8) = o1;
  }
}

// ---- k_L0: layer-0 GEMM -> H0[eb][sortedRow][256] bf16 ----
// Block: 128 atoms x 128 W-cols, one (s, eb). 512 thr = 8 waves; wave = 1
// atom-tile(16) x 8 n-tiles. Operand-swapped MFMA (A-op = W-frag, B-op =
// atom-frag) so D cols = atoms -> coalesced row-major H0 stores.
// A via LDS dbuf (20KB); W-frags global (x8 wave redundancy -> L1 dedupe).
__global__ __launch_bounds__(512, 4) void k_L0(
    const void* __restrict__ aev, const u16* __restrict__ wt0,
    const u16* __restrict__ b0b, u16* __restrict__ H0,
    const int* __restrict__ w, const int* __restrict__ order, int ePhase) {
  __shared__ __align__(16) u16 ach[2][128 * 40];
  __shared__ int aid[128];
  const int tid = threadIdx.x;
  const int g = blockIdx.x;
  const int s = g >> 1;
  const int y = blockIdx.y;
  const int eb = (g & 1) * 2 + ((y >> 1) & 1);
  const int nh = y & 1;
  const int tile = y >> 2;
  const int cnt = w[s];
  if (tile * 128 >= cnt) return;
  const bool isF32 = (w[18] != 0);
  const int mBase = w[13 + s] + tile * 128;
  const int sEnd = w[13 + s] + cnt;
  const int se = s * NE + ePhase + eb;

  if (tid < 128) aid[tid] = (tile * 128 + tid < cnt) ? order[mBase + tid] : -1;
  __syncthreads();

  const int lane = tid & 63;
  const int wv = tid >> 6;       // atom-tile 0..7
  const int lcol = lane & 15;
  const int quad = lane >> 4;

  const int sm = tid >> 2;       // staging row 0..127
  const int sk = (tid & 3) * 8;  // staging k-offset
  const int sa = aid[sm];

  f32x4 acc[8];
#pragma unroll
  for (int j = 0; j < 8; ++j) acc[j] = (f32x4){0.f, 0.f, 0.f, 0.f};

  const u16* wb = wt0 + (size_t)se * 256 * 1024 + (size_t)(nh * 128 + lcol) * 1024 + quad * 8;
  // stage chunk 0
  *(u16x8*)(&ach[0][sm * 40 + sk]) = loadA8(aev, sa, sk, isF32);
  __syncthreads();

  for (int kc = 0; kc < 32; ++kc) {
    const int d = kc & 1;
    u16x8 aNx;
    if (kc < 31) aNx = loadA8(aev, sa, (kc + 1) * 32 + sk, isF32);
    s16x8 aFb = __builtin_bit_cast(s16x8,
        *(const u16x8*)(&ach[d][(wv * 16 + lcol) * 40 + quad * 8]));
#pragma unroll
    for (int g2 = 0; g2 < 2; ++g2) {
      u16x8 Wc[4];
#pragma unroll
      for (int j = 0; j < 4; ++j)
        Wc[j] = *(const u16x8*)(wb + (size_t)((g2 * 4 + j) * 16) * 1024 + kc * 32);
#pragma unroll
      for (int j = 0; j < 4; ++j)
        acc[g2 * 4 + j] = __builtin_amdgcn_mfma_f32_16x16x32_bf16(
            __builtin_bit_cast(s16x8, Wc[j]), aFb, acc[g2 * 4 + j], 0, 0, 0);
    }
    if (kc < 31) {
      *(u16x8*)(&ach[d ^ 1][sm * 40 + sk]) = aNx;
      __syncthreads();
    }
  }
  // epilogue: bias + CELU, store bf16x4 per lane (row = atom, cols = 4 n)
  const int row = mBase + wv * 16 + lcol;
  if (row < sEnd) {
    u16* hrow = H0 + ((size_t)eb * RP + row) * 256;
#pragma unroll
    for (int nt = 0; nt < 8; ++nt) {
      int n0 = nh * 128 + nt * 16 + quad * 4;
      u16x4 bb4 = *(const u16x4*)(b0b + se * 256 + n0);
      u16x4 o;
#pragma unroll
      for (int r = 0; r < 4; ++r) o[r] = f2bf(celu_f(acc[nt][r] + bf2f(bb4[r])));
      *(u16x4*)(hrow + n0) = o;
    }
  }
}

// ---- k_L123: layers 1-3 fused. M=64 atoms, 256 thr = 4 waves; wave = 1
// atom-tile x all n-tiles. A-frags from global H0; H1/H2 in LDS (r5-proven
// orientation: mfma(atomFrag, wFrag): D row=quad*4+r (atom), col=lcol (n)).
__global__ __launch_bounds__(256, 4) void k_L123(
    const u16* __restrict__ H0, const u16* __restrict__ wt1, const u16* __restrict__ wt2,
    const u16* __restrict__ w3b, const u16* __restrict__ b1b, const u16* __restrict__ b2b,
    const u16* __restrict__ b3b, const int* __restrict__ w, float* __restrict__ accum,
    int ePhase) {
  __shared__ __align__(16) u16 H1[64][200];
  __shared__ u16 W3s[160];
  __shared__ float red[256];
  const int tid = threadIdx.x;
  const int g = blockIdx.x;
  const int s = g >> 1;
  const int y = blockIdx.y;
  const int eb = (g & 1) * 2 + (y & 1);
  const int tile = y >> 1;
  const int cnt = w[s];
  if (tile * 64 >= cnt) return;
  const int mBase = w[13 + s] + tile * 64;
  const int mCount = min(64, cnt - tile * 64);
  const int se = s * NE + ePhase + eb;

  if (tid < 160) W3s[tid] = w3b[se * 160 + tid];

  const int lane = tid & 63;
  const int wv = tid >> 6;   // atom-tile 0..3
  const int lcol = lane & 15;
  const int quad = lane >> 4;

  // ---- layer 1: H0[64x256] @ W1t[192][256] ----
  f32x4 acc[12];
#pragma unroll
  for (int j = 0; j < 12; ++j) acc[j] = (f32x4){0.f, 0.f, 0.f, 0.f};
  const u16* arow = H0 + ((size_t)eb * RP + mBase + wv * 16 + lcol) * 256 + quad * 8;
  const u16* wb1 = wt1 + (size_t)se * 192 * 256 + (size_t)lcol * 256 + quad * 8;
  for (int kc = 0; kc < 8; ++kc) {
    s16x8 aF = __builtin_bit_cast(s16x8, *(const u16x8*)(arow + kc * 32));
#pragma unroll
    for (int g2 = 0; g2 < 3; ++g2) {
      u16x8 Wc[4];
#pragma unroll
      for (int j = 0; j < 4; ++j)
        Wc[j] = *(const u16x8*)(wb1 + (size_t)((g2 * 4 + j) * 16) * 256 + kc * 32);
#pragma unroll
      for (int j = 0; j < 4; ++j)
        acc[g2 * 4 + j] = __builtin_amdgcn_mfma_f32_16x16x32_bf16(
            aF, __builtin_bit_cast(s16x8, Wc[j]), acc[g2 * 4 + j], 0, 0, 0);
    }
  }
#pragma unroll
  for (int nt = 0; nt < 12; ++nt) {
    int n = nt * 16 + lcol;
    float bb = bf2f(b1b[se * 192 + n]);
#pragma unroll
    for (int r = 0; r < 4; ++r)
      H1[wv * 16 + quad * 4 + r][n] = f2bf(celu_f(acc[nt][r] + bb));
  }
  __syncthreads();

  // ---- layer 2: H1[64x192] @ W2t[160][192] ----
#pragma unroll
  for (int j = 0; j < 10; ++j) acc[j] = (f32x4){0.f, 0.f, 0.f, 0.f};
  const u16* wb2 = wt2 + (size_t)se * 160 * 192 + (size_t)lcol * 192 + quad * 8;
  for (int kc = 0; kc < 6; ++kc) {
    s16x8 aF = __builtin_bit_cast(s16x8,
        *(const u16x8*)(&H1[wv * 16 + lcol][kc * 32 + quad * 8]));
#pragma unroll
    for (int g2 = 0; g2 < 3; ++g2) {
      const int nn = (g2 < 2) ? 4 : 2;
      u16x8 Wc[4];
      for (int j = 0; j < nn; ++j)
        Wc[j] = *(const u16x8*)(wb2 + (size_t)((g2 * 4 + j) * 16) * 192 + kc * 32);
      for (int j = 0; j < nn; ++j)
        acc[g2 * 4 + j] = __builtin_amdgcn_mfma_f32_16x16x32_bf16(
            aF, __builtin_bit_cast(s16x8, Wc[j]), acc[g2 * 4 + j], 0, 0, 0);
    }
  }
  __syncthreads();  // all H1 reads done; reuse as H2
#pragma unroll
  for (int nt = 0; nt < 10; ++nt) {
    int n = nt * 16 + lcol;
    float bb = bf2f(b2b[se * 160 + n]);
#pragma unroll
    for (int r = 0; r < 4; ++r)
      H1[wv * 16 + quad * 4 + r][n] = f2bf(celu_f(acc[nt][r] + bb));
  }
  __syncthreads();

  // ---- layer 3: dot(H2[64x160], W3) + b3, reduce ----
  {
    int m = tid >> 2, part = tid & 3;
    float p = 0.f;
#pragma unroll
    for (int k0 = 0; k0 < 40; ++k0) {
      int k = part * 40 + k0;
      p = fmaf(bf2f(H1[m][k]), bf2f(W3s[k]), p);
    }
    red[tid] = p;
  }
  __syncthreads();
  if (tid < 64) {
    float b3v = bf2f(b3b[se]);
    float v = 0.f;
    if (tid < mCount) {
      v = red[4 * tid] + red[4 * tid + 1] + red[4 * tid + 2] + red[4 * tid + 3] + b3v;
    }
#pragma unroll
    for (int off = 32; off > 0; off >>= 1) v += __shfl_down(v, off);
    if (tid == 0) atomicAdd(accum, v * 0.125f);
  }
}

__global__ void k_final(const float* __restrict__ accum, u32* __restrict__ out) {
  u32 h = (u32)f2bf(accum[0]);
  out[0] = (h << 16) | h;  // correct under bf16 or fp32 readback
}

extern "C" void kernel_launch(void* const* d_in, const int* in_sizes, int n_in,
                              void* d_out, int out_size, void* d_ws, size_t ws_size,
                              hipStream_t stream) {
  const void* aev = d_in[0];
  const void* species = d_in[1];
  const void* W0 = d_in[2];
  const void* b0 = d_in[3];
  const void* W1 = d_in[4];
  const void* b1 = d_in[5];
  const void* W2 = d_in[6];
  const void* b2 = d_in[7];
  const void* W3 = d_in[8];
  const void* b3 = d_in[9];

  int* wsI = (int*)d_ws;
  float* accum = (float*)((char*)d_ws + 17 * 4);
  int* order = wsI + 1024;
  char* wsB = (char*)d_ws;

  // byte offsets (total ~63.5MB; round-4 proved ws_size >= 64.0MB)
  size_t oWt0 = 262144;                              // 32x256x1024x2 = 16.78MB
  size_t oWt1 = oWt0 + 32ull * 256 * 1024 * 2;       // 3.15MB
  size_t oWt2 = oWt1 + 32ull * 192 * 256 * 2;        // 1.97MB
  size_t oW3 = oWt2 + 32ull * 160 * 192 * 2;
  size_t oB0 = oW3 + 32 * 160 * 2;
  size_t oB1 = oB0 + 32 * 256 * 2;
  size_t oB2 = oB1 + 32 * 192 * 2;
  size_t oB3 = oB2 + 32 * 160 * 2;
  size_t oH0 = (oB3 + 64 * 2 + 255) & ~(size_t)255;  // 4 x RP x 256 x 2 = 41.2MB

  u16* wt0 = (u16*)(wsB + oWt0);
  u16* wt1 = (u16*)(wsB + oWt1);
  u16* wt2 = (u16*)(wsB + oWt2);
  u16* w3b = (u16*)(wsB + oW3);
  u16* b0b = (u16*)(wsB + oB0);
  u16* b1b = (u16*)(wsB + oB1);
  u16* b2b = (u16*)(wsB + oB2);
  u16* b3b = (u16*)(wsB + oB3);
  u16* H0 = (u16*)(wsB + oH0);

  hipLaunchKernelGGL(k_sort, dim3(1), dim3(1024), 0, stream, aev, species, wsI, order);
  hipLaunchKernelGGL(k_prep, dim3(2721), dim3(256), 0, stream, W0, W1, W2, b0, b1, b2, b3, W3,
                     wt0, wt1, wt2, b0b, b1b, b2b, b3b, w3b, wsI);
  for (int ph = 0; ph < 2; ++ph) {
    hipLaunchKernelGGL(k_L0, dim3(8, 628), dim3(512), 0, stream,
                       aev, wt0, b0b, H0, wsI, order, ph * 4);
    hipLaunchKernelGGL(k_L123, dim3(8, 626), dim3(256), 0, stream,
                       H0, wt1, wt2, w3b, b1b, b2b, b3b, wsI, accum, ph * 4);
  }
  hipLaunchKernelGGL(k_final, dim3(1), dim3(1), 0, stream, accum, (u32*)d_out);
}